// Round 4
// baseline (87.114 us; speedup 1.0000x reference)
//
#include <hip/hip_runtime.h>
#include <math.h>

#define NBS 2
#define NPTS 4096
#define HH 64
#define WW 192
#define HW (HH*WW)        // 12288
#define NC 64
#define CH 8              // point chunks
#define CSZ (NPTS/CH)     // 512
#define NTILES (HW/64)    // 192

#define FBIG 3.0e38f

// sorted top-3 insert, strict < (ties keep earlier => lower index wins,
// matching lax.top_k, given ascending-index encounter order)
#define INSERT3(dv, gi)                                   \
  if ((dv) < v2) {                                        \
    if ((dv) < v1) {                                      \
      v2 = v1; i2 = i1;                                   \
      if ((dv) < v0) { v1 = v0; i1 = i0; v0 = (dv); i0 = (gi); } \
      else           { v1 = (dv); i1 = (gi); }            \
    } else { v2 = (dv); i2 = (gi); }                      \
  }

// ---------------- K0: pack points (2u0,2u1,uu) + transpose feat_3d ----------
__global__ __launch_bounds__(256) void k0_prep(
    const float* __restrict__ uv, const float* __restrict__ f3d,
    float4* __restrict__ pts, float* __restrict__ f3dT) {
#pragma clang fp contract(off)
  int bid = blockIdx.x;
  int t = threadIdx.x;
  if (bid < 128) {
    // transpose 64n x 64c tile: b = bid/64, ntile = bid%64
    int b = bid >> 6;
    int nt = (bid & 63) << 6;
    __shared__ float tile[64][65];
    int n_in = t & 63;
    int r0 = t >> 6;                       // 0..3
    const float* src = f3d + (size_t)b * NC * NPTS;
#pragma unroll
    for (int r = 0; r < 16; ++r) {
      int c = r0 + (r << 2);
      tile[c][n_in] = src[(size_t)c * NPTS + nt + n_in];
    }
    __syncthreads();
    float* dst = f3dT + ((size_t)b * NPTS + nt) * NC;
    int c_out = t & 63;
#pragma unroll
    for (int r = 0; r < 16; ++r) {
      int n = r0 + (r << 2);
      dst[(size_t)n * NC + c_out] = tile[c_out][n];
    }
  } else {
    int i = (bid - 128) * 256 + t;         // 0..8191
    if (i < NBS * NPTS) {
      int b = i >> 12, n = i & (NPTS - 1);
      float u0 = uv[(size_t)b * 2 * NPTS + n];
      float u1 = uv[(size_t)b * 2 * NPTS + NPTS + n];
      // uu = rnd(rnd(u0^2) + rnd(u1^2)) : matches sum(uv*uv, axis=1)
      // contract(off) guarantees two v_mul + v_add, NO fmac fusion.
      float s0 = u0 * u0;
      float s1 = u1 * u1;
      float uu = s0 + s1;
      pts[i] = make_float4(u0 + u0, u1 + u1, uu, 0.0f);  // 2x exact
    }
  }
}

// ---------------- K1: chunked brute-force 3-NN ------------------------------
__global__ __launch_bounds__(64) void k1_knn(
    const float4* __restrict__ pts, float2* __restrict__ part) {
#pragma clang fp contract(off)
  int T = blockIdx.x;         // pixel tile
  int ch = blockIdx.y;        // point chunk
  int b = blockIdx.z;
  int lane = threadIdx.x;
  int q = T * 64 + lane;
  float xf = (float)(q % WW);
  float yf = (float)(q / WW);
  // gg = x^2 + y^2 is an exact small integer in fp32
  float gg = xf * xf + yf * yf;

  __shared__ float4 sh[CSZ];
  const float4* src = pts + (size_t)b * NPTS + ch * CSZ;
  for (int i = lane; i < CSZ; i += 64) sh[i] = src[i];
  __syncthreads();

  float v0 = FBIG, v1 = FBIG, v2 = FBIG;
  int i0 = 0, i1 = 0, i2 = 0;
#pragma unroll 4
  for (int n = 0; n < CSZ; ++n) {
    float4 p = sh[n];
    // golden (XLA-CPU Eigen / numpy-FMA) contracts c=2 ascending:
    //   dot = fma(y, u1, rnd(x*u0));   2*dot exact via pre-scaled (2u0,2u1)
    float m0 = xf * p.x;                       // rnd(x*2u0) = 2*rnd(x*u0)
    float dot2 = __builtin_fmaf(yf, p.y, m0);  // 2*fma(y,u1,rnd(x*u0))
    float t1 = gg + p.z;                       // rnd(gg+uu)
    float d = t1 - dot2;                       // Sterbenz-exact near min
    if (d < v2) {
      int gi = (ch << 9) + n;
      if (d < v1) {
        v2 = v1; i2 = i1;
        if (d < v0) { v1 = v0; i1 = i0; v0 = d; i0 = gi; }
        else        { v1 = d; i1 = gi; }
      } else { v2 = d; i2 = gi; }
    }
  }
  size_t row = ((size_t)(b * NTILES + T) * CH + ch) * 3;
  part[(row + 0) * 64 + lane] = make_float2(v0, __int_as_float(i0));
  part[(row + 1) * 64 + lane] = make_float2(v1, __int_as_float(i1));
  part[(row + 2) * 64 + lane] = make_float2(v2, __int_as_float(i2));
}

// ---------------- K2: merge + offsets + MLP + weighted sum ------------------
__global__ __launch_bounds__(64) void k2_mlp(
    const float2* __restrict__ part, const float* __restrict__ uv,
    const float* __restrict__ f3dT,
    const float* __restrict__ w1, const float* __restrict__ b1,
    const float* __restrict__ w2, const float* __restrict__ b2,
    float4* __restrict__ finalW) {
  int T = blockIdx.x;
  int b = blockIdx.y;
  int lane = threadIdx.x;
  int q = T * 64 + lane;
  float xf = (float)(q % WW);
  float yf = (float)(q / WW);

  // merge 8 chunks x 3 candidates (stream order guarantees ascending idx ties)
  float v0 = FBIG, v1 = FBIG, v2 = FBIG;
  int i0 = 0, i1 = 0, i2 = 0;
  size_t rowBase = (size_t)(b * NTILES + T) * CH * 3;
  for (int c = 0; c < CH * 3; ++c) {
    float2 cnd = part[(rowBase + c) * 64 + lane];
    float d = cnd.x;
    int gi = __float_as_int(cnd.y);
    INSERT3(d, gi);
  }
  int idx[3] = {i0, i1, i2};

  float h1a[3][16];
#pragma unroll
  for (int k = 0; k < 3; ++k) {
    int i = idx[k];
    float u0 = uv[(size_t)b * 2 * NPTS + i];
    float u1 = uv[(size_t)b * 2 * NPTS + NPTS + i];
    float dx = u0 - xf;
    float dy = u1 - yf;
    float nrm = sqrtf(dx * dx + dy * dy);
#pragma unroll
    for (int o = 0; o < 16; ++o) {
      float h = fmaf(w1[o * 3 + 0], dx,
               fmaf(w1[o * 3 + 1], dy,
               fmaf(w1[o * 3 + 2], nrm, b1[o])));
      h1a[k][o] = (h >= 0.0f) ? h : 0.1f * h;
    }
  }

  const float4* f0 = (const float4*)(f3dT + ((size_t)b * NPTS + idx[0]) * NC);
  const float4* f1 = (const float4*)(f3dT + ((size_t)b * NPTS + idx[1]) * NC);
  const float4* f2 = (const float4*)(f3dT + ((size_t)b * NPTS + idx[2]) * NC);

  for (int c4 = 0; c4 < 16; ++c4) {
    float4 a = f0[c4], bb = f1[c4], cc4 = f2[c4];
    float fa[4] = {a.x, a.y, a.z, a.w};
    float fb[4] = {bb.x, bb.y, bb.z, bb.w};
    float fc[4] = {cc4.x, cc4.y, cc4.z, cc4.w};
    float res[4];
#pragma unroll
    for (int cc = 0; cc < 4; ++cc) {
      int c = c4 * 4 + cc;
      float bias = b2[c];
      float s0 = bias, s1 = bias, s2 = bias;
#pragma unroll
      for (int o = 0; o < 16; ++o) {
        float w = w2[c * 16 + o];
        s0 = fmaf(w, h1a[0][o], s0);
        s1 = fmaf(w, h1a[1][o], s1);
        s2 = fmaf(w, h1a[2][o], s2);
      }
      float g0 = 1.0f / (1.0f + __expf(-s0));
      float g1 = 1.0f / (1.0f + __expf(-s1));
      float g2 = 1.0f / (1.0f + __expf(-s2));
      res[cc] = g0 * fa[cc] + g1 * fb[cc] + g2 * fc[cc];
    }
    finalW[((size_t)b * HW + q) * 16 + c4] =
        make_float4(res[0], res[1], res[2], res[3]);
  }
}

// ---------------- K3: out = leaky(w_out @ final + b_out) --------------------
__global__ __launch_bounds__(256) void k3_out(
    const float* __restrict__ finalW, const float* __restrict__ w_out,
    const float* __restrict__ b_out, float* __restrict__ out) {
  int blk = blockIdx.x;             // 0..383
  int b = blk / NTILES;
  int T = blk % NTILES;
  int q0 = T * 64;
  int t = threadIdx.x;
  int px = t & 63;

  __shared__ float fin[64][65];
  {
    int p = t >> 2;
    int cs = (t & 3) * 16;
    const float* srcp = finalW + ((size_t)b * HW + q0 + p) * NC + cs;
#pragma unroll
    for (int r = 0; r < 16; ++r) fin[p][cs + r] = srcp[r];
  }
  __syncthreads();

  int o0 = __builtin_amdgcn_readfirstlane((t >> 6) << 4);  // wave-uniform
  float acc[16];
#pragma unroll
  for (int j = 0; j < 16; ++j) acc[j] = b_out[o0 + j];
  for (int c = 0; c < 64; ++c) {
    float f = fin[px][c];
#pragma unroll
    for (int j = 0; j < 16; ++j)
      acc[j] = fmaf(w_out[(o0 + j) * 64 + c], f, acc[j]);
  }
  float* dst = out + ((size_t)(b * 64 + o0)) * HW + q0 + px;
#pragma unroll
  for (int j = 0; j < 16; ++j) {
    float v = acc[j];
    dst[(size_t)j * HW] = (v >= 0.0f) ? v : 0.1f * v;
  }
}

extern "C" void kernel_launch(void* const* d_in, const int* in_sizes, int n_in,
                              void* d_out, int out_size, void* d_ws, size_t ws_size,
                              hipStream_t stream) {
  const float* uv   = (const float*)d_in[0];
  // d_in[1] = feat_2d : values unused by the reference (shape only)
  const float* f3d  = (const float*)d_in[2];
  const float* w1   = (const float*)d_in[3];
  const float* b1   = (const float*)d_in[4];
  const float* w2   = (const float*)d_in[5];
  const float* b2   = (const float*)d_in[6];
  const float* wout = (const float*)d_in[7];
  const float* bout = (const float*)d_in[8];
  float* out = (float*)d_out;

  char* ws = (char*)d_ws;
  float4* pts    = (float4*)(ws);               // 2*4096*16      = 131072 B
  float*  f3dT   = (float*)(ws + 131072);       // 2*4096*64*4    = 2097152 B
  float2* part   = (float2*)(ws + 2228224);     // 2*192*8*3*64*8 = 4718592 B
  float4* finalW = (float4*)(ws + 6946816);     // 2*12288*64*4   = 6291456 B

  hipLaunchKernelGGL(k0_prep, dim3(160), dim3(256), 0, stream, uv, f3d, pts, f3dT);
  hipLaunchKernelGGL(k1_knn, dim3(NTILES, CH, NBS), dim3(64), 0, stream, pts, part);
  hipLaunchKernelGGL(k2_mlp, dim3(NTILES, NBS), dim3(64), 0, stream,
                     part, uv, f3dT, w1, b1, w2, b2, finalW);
  hipLaunchKernelGGL(k3_out, dim3(NTILES * NBS), dim3(256), 0, stream,
                     (const float*)finalW, wout, bout, out);
}